// Round 10
// baseline (286.619 us; speedup 1.0000x reference)
//
#include <hip/hip_runtime.h>

#define NUM_E   16384
#define DIM     256
#define NROWS   8192      // B*H*W
#define HW      1024      // H*W
#define BM      128
#define BN      256
#define BK      32
#define NCB     (NUM_E / BN)   // 64 col blocks
#define GATE    2e-3f     // flag threshold (~7 sigma of bf16 pairwise err)
#define TAUC    2e-3f     // candidate-qualify threshold
#define EHID    2e-3      // hidden-code margin
#define MAXC    16

// 16-B chunk swizzle for staging (chunks 0..3 within a 32-short row)
#define SWZ(r) ((((r) >> 1) ^ ((r) >> 3)) & 3)

typedef __bf16 bf16x8 __attribute__((ext_vector_type(8)));
typedef float  f32x4  __attribute__((ext_vector_type(4)));
typedef float  f32x16 __attribute__((ext_vector_type(16)));

__device__ __forceinline__ unsigned short f2bf(float x) {
    unsigned u = __float_as_uint(x);
    unsigned r = (u + 0x7fffu + ((u >> 16) & 1u)) >> 16;
    return (unsigned short)r;
}
__device__ __forceinline__ void async_copy16(const void* g, void* l) {
    __builtin_amdgcn_global_load_lds(
        (const __attribute__((address_space(1))) unsigned int*)g,
        (__attribute__((address_space(3))) unsigned int*)l, 16, 0, 0);
}

// ---------------- prep z (fused norms): one z pass, bf16 hi split ----------------
__global__ void k_prep_z(const float* __restrict__ z, unsigned short* __restrict__ Zh) {
    __shared__ float T[256 * 68];       // [c][n] tile, pad 68
    __shared__ float Tinv[64];
    int t = threadIdx.x;
    int n0 = blockIdx.x * 64;
    int b = n0 >> 10, hw0 = n0 & 1023;
    #pragma unroll
    for (int i = 0; i < 16; i++) {
        int f = t + 256 * i;            // 0..4095
        int cc = f >> 4, n4 = (f & 15) * 4;
        float4 v = *(const float4*)(z + (size_t)(b * DIM + cc) * HW + hw0 + n4);
        *(float4*)&T[cc * 68 + n4] = v;
    }
    __syncthreads();
    {   // row sums: 4 threads per row, 64 c's each
        int rl = t >> 2, q = t & 3;
        float s = 0.f;
        #pragma unroll
        for (int c = q * 64; c < q * 64 + 64; c++) {
            float v = T[c * 68 + rl];
            s += v * v;
        }
        s += __shfl_down(s, 1);
        s += __shfl_down(s, 2);
        if (q == 0) Tinv[rl] = 1.0f / fmaxf(sqrtf(s), 1e-12f);
    }
    __syncthreads();
    #pragma unroll
    for (int i = 0; i < 16; i++) {
        int f = t + 256 * i;
        int nn = f >> 6, c4 = (f & 63) * 4;
        float iv = Tinv[nn];
        ushort4 h;
        h.x = f2bf(T[(c4+0)*68 + nn] * iv);
        h.y = f2bf(T[(c4+1)*68 + nn] * iv);
        h.z = f2bf(T[(c4+2)*68 + nn] * iv);
        h.w = f2bf(T[(c4+3)*68 + nn] * iv);
        *(ushort4*)(Zh + (size_t)(n0 + nn) * DIM + c4) = h;
    }
}

// ---------------- prep e: fp64 norm + bf16 hi ----------------
__global__ void k_prep_e(const float* __restrict__ emb, float* __restrict__ inv_e,
                         double* __restrict__ se2, unsigned short* __restrict__ Eh,
                         int* __restrict__ cnt2) {
    if (blockIdx.x == 0 && threadIdx.x == 0) *cnt2 = 0;
    int wv = threadIdx.x >> 6, lane = threadIdx.x & 63;
    int k = blockIdx.x * 4 + wv;
    float4 v = *(const float4*)(emb + (size_t)k * DIM + lane * 4);
    double sq = (double)v.x*v.x + (double)v.y*v.y + (double)v.z*v.z + (double)v.w*v.w;
    for (int off = 32; off > 0; off >>= 1) sq += __shfl_down(sq, off);
    double tot = fmax(__shfl(sq, 0), 1e-24);
    if (lane == 0) { se2[k] = tot; inv_e[k] = 1.0f / fmaxf((float)sqrt(tot), 1e-12f); }
    float s = 1.0f / fmaxf((float)sqrt(tot), 1e-12f);
    ushort4 h;
    h.x = f2bf(v.x * s); h.y = f2bf(v.y * s); h.z = f2bf(v.z * s); h.w = f2bf(v.w * s);
    *(ushort4*)(Eh + (size_t)k * DIM + lane * 4) = h;
}

// ---------------- MFMA bf16 score, butterfly epilogue, 24 KB LDS ----------------
__launch_bounds__(256, 3)
__global__ void k_score(const unsigned short* __restrict__ Zh,
                        const unsigned short* __restrict__ Eh, f32x4* __restrict__ part) {
    // staging: A 4096 | B 8192 shorts = 24 KB; epilogue merge buf 4 KB (union)
    __shared__ __align__(16) unsigned short lds[12288];
    const int t = threadIdx.x, l = t & 63, w = t >> 6;
    const int wm = w >> 1, wn = w & 1;      // wave tile 64 x 128
    const int m0 = blockIdx.x * BM;
    const int nb = blockIdx.y * BN;
    const int l31 = l & 31, lh = l >> 5;
    const int sr = l >> 2, sp = l & 3;

    const unsigned short* gA0 = Zh + (size_t)m0 * DIM;
    const unsigned short* gB0 = Eh + (size_t)nb * DIM;

    f32x16 acc[2][4];
    #pragma unroll
    for (int i = 0; i < 2; i++)
        #pragma unroll
        for (int j = 0; j < 4; j++) acc[i][j] = (f32x16)0.f;

    for (int kc = 0; kc < DIM; kc += BK) {
        #pragma unroll
        for (int h = 0; h < 2; h++) {       // A: 8 subtiles
            int sub = 4 * h + w;
            int r = sub * 16 + sr;
            int c = sp ^ SWZ(r);
            async_copy16(gA0 + (size_t)r * DIM + kc + c * 8, &lds[sub * 512]);
        }
        #pragma unroll
        for (int h = 0; h < 4; h++) {       // B: 16 subtiles
            int sub = 4 * h + w;
            int r = sub * 16 + sr;
            int c = sp ^ SWZ(r);
            async_copy16(gB0 + (size_t)r * DIM + kc + c * 8, &lds[4096 + sub * 512]);
        }
        __syncthreads();
        #pragma unroll
        for (int s = 0; s < 2; s++) {
            int c = 2 * s + lh;
            bf16x8 ah[2], bh[4];
            #pragma unroll
            for (int i = 0; i < 2; i++) {
                int r = wm * 64 + i * 32 + l31;
                ah[i] = *(const bf16x8*)&lds[r * 32 + ((c ^ SWZ(r)) * 8)];
            }
            #pragma unroll
            for (int j = 0; j < 4; j++) {
                int r = wn * 128 + j * 32 + l31;
                bh[j] = *(const bf16x8*)&lds[4096 + r * 32 + ((c ^ SWZ(r)) * 8)];
            }
            #pragma unroll
            for (int i = 0; i < 2; i++)
                #pragma unroll
                for (int j = 0; j < 4; j++)
                    acc[i][j] = __builtin_amdgcn_mfma_f32_32x32x16_bf16(ah[i], bh[j], acc[i][j], 0, 0, 0);
        }
        __syncthreads();
    }

    // ---- epilogue v3: fold j, 5-step butterfly over l31, 4 KB wn-merge ----
    f32x4* mrg = (f32x4*)lds;               // [128][2]
    #pragma unroll
    for (int i = 0; i < 2; i++) {
        #pragma unroll
        for (int reg = 0; reg < 16; reg++) {
            float V1 = -2e9f, V2 = -2e9f; int I1 = 0, I2 = 0;
            #pragma unroll
            for (int j = 0; j < 4; j++) {
                float v = acc[i][j][reg];
                int c = nb + wn * 128 + j * 32 + l31;
                bool g1 = v > V1, g2 = v > V2;
                I2 = g1 ? I1 : (g2 ? c : I2);
                V2 = g1 ? V1 : (g2 ? v : V2);
                I1 = g1 ? c : I1;
                V1 = g1 ? v : V1;
            }
            #pragma unroll
            for (int m = 1; m <= 16; m <<= 1) {
                float oV1 = __shfl_xor(V1, m), oV2 = __shfl_xor(V2, m);
                int   oI1 = __shfl_xor(I1, m), oI2 = __shfl_xor(I2, m);
                bool o1 = oV1 > V1;
                float mn = o1 ? V1 : oV1; int mni = o1 ? I1 : oI1;
                V1 = o1 ? oV1 : V1; I1 = o1 ? oI1 : I1;
                bool s2 = oV2 > V2;
                float m2 = s2 ? oV2 : V2; int m2i = s2 ? oI2 : I2;
                bool c2 = m2 > mn;
                V2 = c2 ? m2 : mn; I2 = c2 ? m2i : mni;
            }
            if (l31 == 0) {
                int row = wm * 64 + i * 32 + (reg & 3) + 8 * (reg >> 2) + 4 * lh;
                f32x4 e; e[0] = V1; e[1] = __int_as_float(I1);
                e[2] = V2; e[3] = __int_as_float(I2);
                mrg[row * 2 + wn] = e;
            }
        }
    }
    __syncthreads();
    if (t < BM) {
        f32x4 a = mrg[t * 2], bq = mrg[t * 2 + 1];
        float V1 = a[0], V2 = a[2]; int I1 = __float_as_int(a[1]), I2 = __float_as_int(a[3]);
        float oV1 = bq[0], oV2 = bq[2];
        int   oI1 = __float_as_int(bq[1]), oI2 = __float_as_int(bq[3]);
        bool o1 = oV1 > V1;
        float mn = o1 ? V1 : oV1; int mni = o1 ? I1 : oI1;
        V1 = o1 ? oV1 : V1; I1 = o1 ? oI1 : I1;
        bool s2 = oV2 > V2;
        float m2 = s2 ? oV2 : V2; int m2i = s2 ? oI2 : I2;
        bool c2 = m2 > mn;
        V2 = c2 ? m2 : mn; I2 = c2 ? m2i : mni;
        f32x4 e; e[0] = V1; e[1] = __int_as_float(I1);
        e[2] = V2; e[3] = __int_as_float(I2);
        part[(size_t)blockIdx.y * NROWS + m0 + t] = e;
    }
}

// ------- reduce + flag near-ties + in-block fp64 candidate rescore (fused) -------
__global__ void k_final(const f32x4* __restrict__ part,
                        const float* __restrict__ z, const float* __restrict__ emb,
                        const double* __restrict__ se2,
                        int* __restrict__ idx_ws, float* __restrict__ out_idx,
                        int* __restrict__ flags2, int* __restrict__ cnt2) {
    __shared__ f32x4 red[8][32];
    __shared__ float bcV1[32];
    __shared__ int   lcc[32];
    __shared__ int   lcand[32][MAXC];
    __shared__ float sv2[8][32];
    __shared__ float mv2[32];
    __shared__ int   fl[32];
    __shared__ int   nf;
    __shared__ double zs[DIM];
    __shared__ double wvv[4];
    __shared__ int    wii[4];
    const int t = threadIdx.x;
    const int nl = t & 31, sc = t >> 5;
    const int n = blockIdx.x * 32 + nl;
    if (t < 32) lcc[t] = 0;
    if (t == 0) nf = 0;
    // phase 1: global top-2 values per row
    float V1 = -2e9f, V2 = -2e9f; int I1 = 0;
    for (int s = sc * 8; s < sc * 8 + 8; s++) {
        f32x4 e = part[(size_t)s * NROWS + n];
        float v1 = e[0]; int i1 = __float_as_int(e[1]); float v2 = e[2];
        V2 = fmaxf(fmaxf(V2, v2), fminf(v1, V1));
        I1 = (v1 > V1) ? i1 : I1;
        V1 = fmaxf(V1, v1);
    }
    f32x4 me; me[0] = V1; me[1] = __int_as_float(I1); me[2] = V2; me[3] = 0.f;
    red[sc][nl] = me;
    __syncthreads();
    float W1 = -2e9f, W2 = -2e9f;
    if (t < 32) {
        int J1 = 0;
        #pragma unroll
        for (int s2 = 0; s2 < 8; s2++) {
            f32x4 e = red[s2][t];
            float v1 = e[0]; int i1 = __float_as_int(e[1]); float v2 = e[2];
            W2 = fmaxf(fmaxf(W2, v2), fminf(v1, W1));
            J1 = (v1 > W1) ? i1 : J1;
            W1 = fmaxf(W1, v1);
        }
        int nn = blockIdx.x * 32 + t;
        idx_ws[nn] = J1;
        out_idx[nn] = (float)J1;
        bcV1[t] = W1;
    }
    __syncthreads();
    // phase 2: collect block-top-2 candidates of qualifying col-blocks
    float thr = bcV1[nl] - TAUC;
    float lv2 = -2e9f;
    for (int s = sc * 8; s < sc * 8 + 8; s++) {
        f32x4 e = part[(size_t)s * NROWS + n];
        if (e[0] >= thr) {
            int pos = atomicAdd(&lcc[nl], 2);
            if (pos < MAXC)     lcand[nl][pos]     = __float_as_int(e[1]);
            if (pos + 1 < MAXC) lcand[nl][pos + 1] = __float_as_int(e[3]);
            lv2 = fmaxf(lv2, e[2]);
        }
    }
    sv2[sc][nl] = lv2;
    __syncthreads();
    if (t < 32) {
        if (W1 - W2 < GATE) {
            float m = -2e9f;
            #pragma unroll
            for (int s2 = 0; s2 < 8; s2++) m = fmaxf(m, sv2[s2][t]);
            mv2[t] = m;
            int p = atomicAdd(&nf, 1);
            fl[p] = t;
        }
    }
    __syncthreads();
    // phase 3: fp64 rescore of this block's flagged rows
    const int NF = nf;
    const int l = t & 63, w = t >> 6;
    for (int fi = 0; fi < NF; fi++) {
        int nl2 = fl[fi];
        int C = lcc[nl2];
        int n2 = blockIdx.x * 32 + nl2;
        int b = n2 >> 10, hw = n2 & 1023;
        zs[t] = (double)z[(size_t)(b * DIM + t) * HW + hw];
        __syncthreads();
        double best = -2e18; int bi = 0x7fffffff;
        if (C <= MAXC) {
            double z0 = zs[l*4], z1 = zs[l*4+1], z2 = zs[l*4+2], z3 = zs[l*4+3];
            for (int cix = w; cix < C; cix += 4) {
                int k = lcand[nl2][cix];
                float4 ev = *(const float4*)(emb + (size_t)k * DIM + l * 4);
                double d = z0 * (double)ev.x + z1 * (double)ev.y
                         + z2 * (double)ev.z + z3 * (double)ev.w;
                #pragma unroll
                for (int o = 32; o > 0; o >>= 1) d += __shfl_down(d, o);
                if (l == 0) {
                    double qv = d / sqrt(se2[k]);
                    if (qv > best || (qv == best && k < bi)) { best = qv; bi = k; }
                }
            }
        }
        if (l == 0) { wvv[w] = best; wii[w] = bi; }
        __syncthreads();
        if (t == 0) {
            if (C > MAXC) {
                flags2[atomicAdd(cnt2, 1)] = n2;
            } else {
                double B = wvv[0]; int BI = wii[0];
                #pragma unroll
                for (int x = 1; x < 4; x++)
                    if (wvv[x] > B || (wvv[x] == B && wii[x] < BI)) { B = wvv[x]; BI = wii[x]; }
                if ((double)mv2[nl2] >= B - EHID) {
                    flags2[atomicAdd(cnt2, 1)] = n2;   // possible hidden code
                } else {
                    idx_ws[n2] = BI; out_idx[n2] = (float)BI;
                }
            }
        }
        __syncthreads();
    }
}

// ---------------- rare fallback: full fp64 scan (parallel over row x split) ------
__launch_bounds__(256)
__global__ void k_fullscan_part(const int* __restrict__ flags2, const int* __restrict__ cnt2,
                                const float* __restrict__ z, const float* __restrict__ emb,
                                const double* __restrict__ se2, double2* __restrict__ partial) {
    __shared__ double zs[DIM];
    __shared__ double wv[4];
    __shared__ int    wi[4];
    const int t = threadIdx.x, l = t & 63, w = t >> 6;
    const int W = (*cnt2) * 64;
    for (int item = blockIdx.x; item < W; item += gridDim.x) {
        int f = item >> 6, split = item & 63;
        int n = flags2[f];
        int b = n >> 10, hw = n & 1023;
        __syncthreads();
        zs[t] = (double)z[(size_t)(b * DIM + t) * HW + hw];
        __syncthreads();
        double z0 = zs[l*4], z1 = zs[l*4+1], z2 = zs[l*4+2], z3 = zs[l*4+3];
        double best = -2e18; int bi = 0;
        int kbase = split * 256 + w * 64;
        for (int p = 0; p < 64; p++) {
            int k = kbase + p;
            float4 ev = *(const float4*)(emb + (size_t)k * DIM + l * 4);
            double d = z0 * (double)ev.x + z1 * (double)ev.y
                     + z2 * (double)ev.z + z3 * (double)ev.w;
            #pragma unroll
            for (int o = 32; o > 0; o >>= 1) d += __shfl_down(d, o);
            if (l == 0) {
                double qv = d / sqrt(se2[k]);
                if (qv > best) { best = qv; bi = k; }
            }
        }
        if (l == 0) { wv[w] = best; wi[w] = bi; }
        __syncthreads();
        if (t == 0) {
            double B = wv[0]; int BI = wi[0];
            #pragma unroll
            for (int x = 1; x < 4; x++)
                if (wv[x] > B || (wv[x] == B && wi[x] < BI)) { B = wv[x]; BI = wi[x]; }
            partial[item] = make_double2(B, (double)BI);
        }
        __syncthreads();
    }
}

__global__ void k_fullscan_merge(const int* __restrict__ flags2, const int* __restrict__ cnt2,
                                 const double2* __restrict__ partial,
                                 int* __restrict__ idx_ws, float* __restrict__ out_idx) {
    const int F = *cnt2;
    const int l = threadIdx.x & 63, w = threadIdx.x >> 6;
    for (int f = blockIdx.x * 4 + w; f < F; f += gridDim.x * 4) {
        double2 e = partial[(size_t)f * 64 + l];
        double v = e.x; int i = (int)e.y;
        #pragma unroll
        for (int o = 32; o > 0; o >>= 1) {
            double ov = __shfl_down(v, o);
            int    oi = __shfl_down(i, o);
            if (ov > v || (ov == v && oi < i)) { v = ov; i = oi; }
        }
        if (l == 0) { int n = flags2[f]; idx_ws[n] = i; out_idx[n] = (float)i; }
    }
}

// ---------------- gather z_q = emb[idx] * inv_e[idx], grid (32, 8) ----------------
__global__ void k_zq(const int* __restrict__ idx_ws, const float* __restrict__ emb,
                     const float* __restrict__ inv_e, float* __restrict__ zq) {
    int t = threadIdx.x;
    int n = blockIdx.x * 256 + t;
    int b = n >> 10, hw = n & 1023;
    int c0 = blockIdx.y * 32;
    int id = idx_ws[n];
    float s = inv_e[id];
    const float* er = emb + (size_t)id * DIM;
    #pragma unroll
    for (int cc = 0; cc < 32; cc += 4) {
        float4 a = *(const float4*)(er + c0 + cc);
        zq[(size_t)(b * DIM + c0 + cc + 0) * HW + hw] = a.x * s;
        zq[(size_t)(b * DIM + c0 + cc + 1) * HW + hw] = a.y * s;
        zq[(size_t)(b * DIM + c0 + cc + 2) * HW + hw] = a.z * s;
        zq[(size_t)(b * DIM + c0 + cc + 3) * HW + hw] = a.w * s;
    }
}

extern "C" void kernel_launch(void* const* d_in, const int* in_sizes, int n_in,
                              void* d_out, int out_size, void* d_ws, size_t ws_size,
                              hipStream_t stream) {
    const float* z   = (const float*)d_in[0];
    const float* emb = (const float*)d_in[1];

    unsigned short* Zh = (unsigned short*)d_ws;           // 4 MB
    unsigned short* Eh = Zh + (size_t)NROWS * DIM;        // 8 MB
    float*  inv_e = (float*)(Eh + (size_t)NUM_E * DIM);   // 64 KB
    int*    idx_ws = (int*)(inv_e + NUM_E);               // 32 KB
    double* se2   = (double*)(idx_ws + NROWS);            // 128 KB
    int*    flags2 = (int*)(se2 + NUM_E);                 // 32 KB
    int*    cnt2  = flags2 + NROWS;                       // 4 B

    float* zq      = (float*)d_out;
    float* out_idx = zq + (size_t)NROWS * DIM;
    // part (8 MB) aliases the z_q region; consumed by k_final, then reused for
    // fullscan partials, finally overwritten with z_q by k_zq.
    f32x4*   part    = (f32x4*)zq;
    double2* partial = (double2*)zq;

    k_prep_z <<<NROWS / 64, 256, 0, stream>>>(z, Zh);
    k_prep_e <<<NUM_E / 4, 256, 0, stream>>>(emb, inv_e, se2, Eh, cnt2);
    k_score  <<<dim3(NROWS / BM, NCB), 256, 0, stream>>>(Zh, Eh, part);
    k_final  <<<NROWS / 32, 256, 0, stream>>>(part, z, emb, se2, idx_ws, out_idx,
                                              flags2, cnt2);
    k_fullscan_part<<<2048, 256, 0, stream>>>(flags2, cnt2, z, emb, se2, partial);
    k_fullscan_merge<<<64, 256, 0, stream>>>(flags2, cnt2, partial, idx_ws, out_idx);
    k_zq     <<<dim3(NROWS / 256, 8), 256, 0, stream>>>(idx_ws, emb, inv_e, zq);
}